// Round 1
// baseline (585.757 us; speedup 1.0000x reference)
//
#include <hip/hip_runtime.h>
#include <hip/hip_bf16.h>

// Problem constants (match reference)
#define BB      4
#define SS      4096
#define WW      41
#define SDRN    2048
#define HID     2048
#define NTOK    (BB * SS)
#define EPS_LN  1e-5f

// ---------------------------------------------------------------------------
// Kernel 1: transpose proj_w [HID][SDRN] -> Wt [SDRN][HID]
// Standard 32x32 LDS-tiled transpose, block (32,8).
// ---------------------------------------------------------------------------
__global__ __launch_bounds__(256) void transpose_k(const float* __restrict__ in,
                                                   float* __restrict__ out) {
    __shared__ float tile[32][33];  // +1 pad: no bank conflicts
    int x = blockIdx.x * 32 + threadIdx.x;  // input col (n)
    int y = blockIdx.y * 32 + threadIdx.y;  // input row (h)
#pragma unroll
    for (int j = 0; j < 32; j += 8)
        tile[threadIdx.y + j][threadIdx.x] = in[(size_t)(y + j) * SDRN + x];
    __syncthreads();
    x = blockIdx.y * 32 + threadIdx.x;      // output col (h)
    y = blockIdx.x * 32 + threadIdx.y;      // output row (n)
#pragma unroll
    for (int j = 0; j < 32; j += 8)
        out[(size_t)(y + j) * HID + x] = tile[threadIdx.x][threadIdx.y + j];
}

// ---------------------------------------------------------------------------
// Kernel 2: one block per token. Gather unique rows of Wt, accumulate in
// registers (8 h-values per thread as 2 float4), fused LayerNorm epilogue.
// ---------------------------------------------------------------------------
__global__ __launch_bounds__(256) void sdr_gather_ln(
    const int* __restrict__ ids, const float* __restrict__ Wt,
    const float* __restrict__ gamma, const float* __restrict__ beta,
    float* __restrict__ out) {
    const int token = blockIdx.x;
    const int tid   = threadIdx.x;

    __shared__ int   s_ids[WW];
    __shared__ int   s_keep[WW];
    __shared__ float s_red[8];

    if (tid < WW) s_ids[tid] = ids[(size_t)token * WW + tid];
    __syncthreads();
    if (tid < WW) {
        const int v = s_ids[tid];
        int keep = 1;
        for (int j = 0; j < tid; ++j)
            if (s_ids[j] == v) { keep = 0; break; }
        s_keep[tid] = keep;
    }
    __syncthreads();

    float4 acc0 = {0.f, 0.f, 0.f, 0.f};
    float4 acc1 = {0.f, 0.f, 0.f, 0.f};

    for (int i = 0; i < WW; ++i) {
        if (!s_keep[i]) continue;  // wave-uniform branch
        const float4* row = (const float4*)(Wt + (size_t)s_ids[i] * HID);
        const float4 a = row[tid];        // h = tid*4 .. tid*4+3
        const float4 b = row[256 + tid];  // h = 1024 + tid*4 ..
        acc0.x += a.x; acc0.y += a.y; acc0.z += a.z; acc0.w += a.w;
        acc1.x += b.x; acc1.y += b.y; acc1.z += b.z; acc1.w += b.w;
    }

    // Block reduction for mean / var over 2048 values
    float s  = acc0.x + acc0.y + acc0.z + acc0.w + acc1.x + acc1.y + acc1.z + acc1.w;
    float s2 = acc0.x * acc0.x + acc0.y * acc0.y + acc0.z * acc0.z + acc0.w * acc0.w +
               acc1.x * acc1.x + acc1.y * acc1.y + acc1.z * acc1.z + acc1.w * acc1.w;
#pragma unroll
    for (int off = 1; off < 64; off <<= 1) {
        s  += __shfl_xor(s, off);
        s2 += __shfl_xor(s2, off);
    }
    const int wave = tid >> 6;
    if ((tid & 63) == 0) { s_red[wave] = s; s_red[4 + wave] = s2; }
    __syncthreads();
    const float ts   = s_red[0] + s_red[1] + s_red[2] + s_red[3];
    const float ts2  = s_red[4] + s_red[5] + s_red[6] + s_red[7];
    const float mean = ts * (1.0f / HID);
    const float var  = ts2 * (1.0f / HID) - mean * mean;
    const float rstd = rsqrtf(var + EPS_LN);

    const float4* g4 = (const float4*)gamma;
    const float4* b4 = (const float4*)beta;
    float4*       o4 = (float4*)(out + (size_t)token * HID);
    const float4 g0 = g4[tid], g1 = g4[256 + tid];
    const float4 be0 = b4[tid], be1 = b4[256 + tid];
    float4 r0, r1;
    r0.x = (acc0.x - mean) * rstd * g0.x + be0.x;
    r0.y = (acc0.y - mean) * rstd * g0.y + be0.y;
    r0.z = (acc0.z - mean) * rstd * g0.z + be0.z;
    r0.w = (acc0.w - mean) * rstd * g0.w + be0.w;
    r1.x = (acc1.x - mean) * rstd * g1.x + be1.x;
    r1.y = (acc1.y - mean) * rstd * g1.y + be1.y;
    r1.z = (acc1.z - mean) * rstd * g1.z + be1.z;
    r1.w = (acc1.w - mean) * rstd * g1.w + be1.w;
    o4[tid]       = r0;
    o4[256 + tid] = r1;
}

// ---------------------------------------------------------------------------
// Fallback (no workspace): gather directly from proj_w [HID][SDRN] columns.
// Uncoalesced but correct; only used if ws_size < 16 MiB.
// ---------------------------------------------------------------------------
__global__ __launch_bounds__(256) void sdr_gather_ln_notr(
    const int* __restrict__ ids, const float* __restrict__ W,
    const float* __restrict__ gamma, const float* __restrict__ beta,
    float* __restrict__ out) {
    const int token = blockIdx.x;
    const int tid   = threadIdx.x;

    __shared__ int   s_ids[WW];
    __shared__ int   s_keep[WW];
    __shared__ float s_red[8];

    if (tid < WW) s_ids[tid] = ids[(size_t)token * WW + tid];
    __syncthreads();
    if (tid < WW) {
        const int v = s_ids[tid];
        int keep = 1;
        for (int j = 0; j < tid; ++j)
            if (s_ids[j] == v) { keep = 0; break; }
        s_keep[tid] = keep;
    }
    __syncthreads();

    float acc[8] = {0.f};
    for (int i = 0; i < WW; ++i) {
        if (!s_keep[i]) continue;
        const int id = s_ids[i];
#pragma unroll
        for (int j = 0; j < 8; ++j) {
            const int h = tid * 8 + j;
            acc[j] += W[(size_t)h * SDRN + id];
        }
    }
    float s = 0.f, s2 = 0.f;
#pragma unroll
    for (int j = 0; j < 8; ++j) { s += acc[j]; s2 += acc[j] * acc[j]; }
#pragma unroll
    for (int off = 1; off < 64; off <<= 1) {
        s  += __shfl_xor(s, off);
        s2 += __shfl_xor(s2, off);
    }
    const int wave = tid >> 6;
    if ((tid & 63) == 0) { s_red[wave] = s; s_red[4 + wave] = s2; }
    __syncthreads();
    const float ts   = s_red[0] + s_red[1] + s_red[2] + s_red[3];
    const float ts2  = s_red[4] + s_red[5] + s_red[6] + s_red[7];
    const float mean = ts * (1.0f / HID);
    const float var  = ts2 * (1.0f / HID) - mean * mean;
    const float rstd = rsqrtf(var + EPS_LN);

#pragma unroll
    for (int j = 0; j < 8; ++j) {
        const int h = tid * 8 + j;
        out[(size_t)token * HID + h] = (acc[j] - mean) * rstd * gamma[h] + beta[h];
    }
}

extern "C" void kernel_launch(void* const* d_in, const int* in_sizes, int n_in,
                              void* d_out, int out_size, void* d_ws, size_t ws_size,
                              hipStream_t stream) {
    const int*   ids    = (const int*)d_in[0];
    const float* proj_w = (const float*)d_in[1];
    const float* gamma  = (const float*)d_in[2];
    const float* beta   = (const float*)d_in[3];
    float*       out    = (float*)d_out;

    const size_t need = (size_t)SDRN * HID * sizeof(float);
    if (ws_size >= need) {
        float* Wt = (float*)d_ws;
        dim3 tb(32, 8), tg(SDRN / 32, HID / 32);
        transpose_k<<<tg, tb, 0, stream>>>(proj_w, Wt);
        sdr_gather_ln<<<NTOK, 256, 0, stream>>>(ids, Wt, gamma, beta, out);
    } else {
        sdr_gather_ln_notr<<<NTOK, 256, 0, stream>>>(ids, proj_w, gamma, beta, out);
    }
}

// Round 3
// 199.130 us; speedup vs baseline: 2.9416x; 2.9416x over previous
//
#include <hip/hip_runtime.h>
#include <hip/hip_bf16.h>

// Problem constants (match reference)
#define BB      4
#define SS      4096
#define WW      41
#define SDRN    2048
#define HID     2048
#define NTOK    (BB * SS)
#define EPS_LN  1e-5f
#define NSLICE  4
#define SLICE_H 512   // HID / NSLICE

typedef float f32x4 __attribute__((ext_vector_type(4)));  // native vec for nontemporal

// ws layout: [0, 8MB) Wt bf16 [SDRN][HID]; then float2 partials [NTOK*NSLICE]

// ---------------------------------------------------------------------------
// Kernel 1: transpose+convert proj_w [HID][SDRN] f32 -> Wt [SDRN][HID] bf16
// ---------------------------------------------------------------------------
__global__ __launch_bounds__(256) void transpose_cvt(const float* __restrict__ in,
                                                     __hip_bfloat16* __restrict__ out) {
    __shared__ float tile[32][33];
    int x = blockIdx.x * 32 + threadIdx.x;  // n
    int y = blockIdx.y * 32 + threadIdx.y;  // h
#pragma unroll
    for (int j = 0; j < 32; j += 8)
        tile[threadIdx.y + j][threadIdx.x] = in[(size_t)(y + j) * SDRN + x];
    __syncthreads();
    x = blockIdx.y * 32 + threadIdx.x;      // h
    y = blockIdx.x * 32 + threadIdx.y;      // n
#pragma unroll
    for (int j = 0; j < 32; j += 8)
        out[(size_t)(y + j) * HID + x] = __float2bfloat16(tile[threadIdx.x][threadIdx.y + j]);
}

// ---------------------------------------------------------------------------
// Pass 1: gather + accumulate one 512-wide h-slice per wave's token.
// blockIdx.x & 7 pins the slice to an XCD pair -> 2 MB L2-resident table slice.
// Writes pre-LN x into d_out, per-(token,slice) (sum, sumsq) into partials.
// ---------------------------------------------------------------------------
__global__ __launch_bounds__(256) void sdr_gather_p1(
    const int* __restrict__ ids, const __hip_bfloat16* __restrict__ Wt,
    float* __restrict__ x, float2* __restrict__ partials) {
    const int b     = blockIdx.x;
    const int sub   = b & 1;
    const int slice = (b & 7) >> 1;                 // 4 slices, 2 XCDs each
    const int tg    = ((b >> 3) << 1) | sub;        // token group (4 tokens)
    const int wave  = threadIdx.x >> 6;
    const int lane  = threadIdx.x & 63;
    const int token = tg * 4 + wave;

    // load + dedupe ids, all in-register via shuffles
    int myid = 0;
    if (lane < WW) myid = ids[(size_t)token * WW + lane];
    int keep = (lane < WW) ? 1 : 0;
#pragma unroll
    for (int j = 0; j < WW; ++j) {
        const int idj = __shfl(myid, j);
        if (j < lane && lane < WW && idj == myid) keep = 0;
    }

    float acc[8] = {0.f, 0.f, 0.f, 0.f, 0.f, 0.f, 0.f, 0.f};
    // bf16 pairs: row byte base = id*4096; slice offset = slice*1024; lane: 16B
    const unsigned int* base =
        (const unsigned int*)Wt + (size_t)slice * (SLICE_H / 2) + (size_t)lane * 4;

    for (int i = 0; i < WW; ++i) {
        const int idi = __shfl(myid, i);
        const int ki  = __shfl(keep, i);
        if (!ki) continue;                           // wave-uniform
        const uint4 u = *(const uint4*)(base + (size_t)idi * (HID / 2));
        acc[0] += __uint_as_float(u.x << 16);
        acc[1] += __uint_as_float(u.x & 0xffff0000u);
        acc[2] += __uint_as_float(u.y << 16);
        acc[3] += __uint_as_float(u.y & 0xffff0000u);
        acc[4] += __uint_as_float(u.z << 16);
        acc[5] += __uint_as_float(u.z & 0xffff0000u);
        acc[6] += __uint_as_float(u.w << 16);
        acc[7] += __uint_as_float(u.w & 0xffff0000u);
    }

    // per-wave partial sums for this slice
    float s = 0.f, s2 = 0.f;
#pragma unroll
    for (int j = 0; j < 8; ++j) { s += acc[j]; s2 += acc[j] * acc[j]; }
#pragma unroll
    for (int off = 1; off < 64; off <<= 1) {
        s  += __shfl_xor(s, off);
        s2 += __shfl_xor(s2, off);
    }
    if (lane == 0) {
        float2 p; p.x = s; p.y = s2;
        partials[(size_t)token * NSLICE + slice] = p;
    }

    // write pre-LN x (streaming, nontemporal: don't pollute L2 table slice)
    float* xr = x + (size_t)token * HID + slice * SLICE_H + lane * 8;
    f32x4 v0; v0.x = acc[0]; v0.y = acc[1]; v0.z = acc[2]; v0.w = acc[3];
    f32x4 v1; v1.x = acc[4]; v1.y = acc[5]; v1.z = acc[6]; v1.w = acc[7];
    __builtin_nontemporal_store(v0, (f32x4*)xr);
    __builtin_nontemporal_store(v1, (f32x4*)xr + 1);
}

// ---------------------------------------------------------------------------
// Pass 2: combine partials -> mean/rstd, normalize x in place with gamma/beta.
// ---------------------------------------------------------------------------
__global__ __launch_bounds__(256) void sdr_ln_p2(
    float* __restrict__ x, const float2* __restrict__ partials,
    const float* __restrict__ gamma, const float* __restrict__ beta) {
    const int token = blockIdx.x;
    const int tid   = threadIdx.x;

    float s = 0.f, s2 = 0.f;
#pragma unroll
    for (int j = 0; j < NSLICE; ++j) {
        const float2 p = partials[(size_t)token * NSLICE + j];
        s += p.x; s2 += p.y;
    }
    const float mean = s * (1.0f / HID);
    const float var  = s2 * (1.0f / HID) - mean * mean;
    const float rstd = rsqrtf(var + EPS_LN);

    float4*       xr = (float4*)(x + (size_t)token * HID) + tid * 2;
    const float4* g4 = (const float4*)gamma + tid * 2;
    const float4* b4 = (const float4*)beta  + tid * 2;
    float4 a = xr[0], b = xr[1];
    const float4 g0 = g4[0], g1 = g4[1];
    const float4 be0 = b4[0], be1 = b4[1];
    a.x = (a.x - mean) * rstd * g0.x + be0.x;
    a.y = (a.y - mean) * rstd * g0.y + be0.y;
    a.z = (a.z - mean) * rstd * g0.z + be0.z;
    a.w = (a.w - mean) * rstd * g0.w + be0.w;
    b.x = (b.x - mean) * rstd * g1.x + be1.x;
    b.y = (b.y - mean) * rstd * g1.y + be1.y;
    b.z = (b.z - mean) * rstd * g1.z + be1.z;
    b.w = (b.w - mean) * rstd * g1.w + be1.w;
    xr[0] = a;
    xr[1] = b;
}

// ---------------------------------------------------------------------------
// Fallback (tiny ws): gather directly from proj_w columns, fused LN.
// ---------------------------------------------------------------------------
__global__ __launch_bounds__(256) void sdr_gather_ln_notr(
    const int* __restrict__ ids, const float* __restrict__ W,
    const float* __restrict__ gamma, const float* __restrict__ beta,
    float* __restrict__ out) {
    const int token = blockIdx.x;
    const int tid   = threadIdx.x;

    __shared__ int   s_ids[WW];
    __shared__ int   s_keep[WW];
    __shared__ float s_red[8];

    if (tid < WW) s_ids[tid] = ids[(size_t)token * WW + tid];
    __syncthreads();
    if (tid < WW) {
        const int v = s_ids[tid];
        int keep = 1;
        for (int j = 0; j < tid; ++j)
            if (s_ids[j] == v) { keep = 0; break; }
        s_keep[tid] = keep;
    }
    __syncthreads();

    float acc[8] = {0.f};
    for (int i = 0; i < WW; ++i) {
        if (!s_keep[i]) continue;
        const int id = s_ids[i];
#pragma unroll
        for (int j = 0; j < 8; ++j) {
            const int h = tid * 8 + j;
            acc[j] += W[(size_t)h * SDRN + id];
        }
    }
    float s = 0.f, s2 = 0.f;
#pragma unroll
    for (int j = 0; j < 8; ++j) { s += acc[j]; s2 += acc[j] * acc[j]; }
#pragma unroll
    for (int off = 1; off < 64; off <<= 1) {
        s  += __shfl_xor(s, off);
        s2 += __shfl_xor(s2, off);
    }
    const int wave = tid >> 6;
    if ((tid & 63) == 0) { s_red[wave] = s; s_red[4 + wave] = s2; }
    __syncthreads();
    const float ts   = s_red[0] + s_red[1] + s_red[2] + s_red[3];
    const float ts2  = s_red[4] + s_red[5] + s_red[6] + s_red[7];
    const float mean = ts * (1.0f / HID);
    const float var  = ts2 * (1.0f / HID) - mean * mean;
    const float rstd = rsqrtf(var + EPS_LN);

#pragma unroll
    for (int j = 0; j < 8; ++j) {
        const int h = tid * 8 + j;
        out[(size_t)token * HID + h] = (acc[j] - mean) * rstd * gamma[h] + beta[h];
    }
}

extern "C" void kernel_launch(void* const* d_in, const int* in_sizes, int n_in,
                              void* d_out, int out_size, void* d_ws, size_t ws_size,
                              hipStream_t stream) {
    const int*   ids    = (const int*)d_in[0];
    const float* proj_w = (const float*)d_in[1];
    const float* gamma  = (const float*)d_in[2];
    const float* beta   = (const float*)d_in[3];
    float*       out    = (float*)d_out;

    const size_t wt_bytes   = (size_t)SDRN * HID * sizeof(__hip_bfloat16);   // 8 MB
    const size_t part_bytes = (size_t)NTOK * NSLICE * sizeof(float2);        // 512 KB

    if (ws_size >= wt_bytes + part_bytes) {
        __hip_bfloat16* Wt = (__hip_bfloat16*)d_ws;
        float2* partials   = (float2*)((char*)d_ws + wt_bytes);

        dim3 tb(32, 8), tg(SDRN / 32, HID / 32);
        transpose_cvt<<<tg, tb, 0, stream>>>(proj_w, Wt);
        // 4096 token-groups x 4 slices = 16384 blocks; slice = (b&7)>>1
        sdr_gather_p1<<<NTOK, 256, 0, stream>>>(ids, Wt, out, partials);
        sdr_ln_p2<<<NTOK, 256, 0, stream>>>(out, partials, gamma, beta);
    } else {
        sdr_gather_ln_notr<<<NTOK, 256, 0, stream>>>(ids, proj_w, gamma, beta, out);
    }
}

// Round 5
// 166.965 us; speedup vs baseline: 3.5083x; 1.1926x over previous
//
#include <hip/hip_runtime.h>
#include <hip/hip_bf16.h>

// Problem constants (match reference)
#define BB      4
#define SS      4096
#define WW      41
#define SDRN    2048
#define HID     2048
#define NTOK    (BB * SS)
#define EPS_LN  1e-5f
#define NSLICE  4
#define SLICE_H 512        // HID / NSLICE
#define PADID   SDRN       // index of the all-zeros padding row
#define TROWS   (SDRN + 1) // table rows incl. zero row

typedef float        f32x2 __attribute__((ext_vector_type(2)));
typedef float        f32x4 __attribute__((ext_vector_type(4)));
typedef unsigned int u32x4 __attribute__((ext_vector_type(4)));

static __device__ __forceinline__ unsigned short bf16bits(float f) {
    return __builtin_bit_cast(unsigned short, __float2bfloat16(f));
}

// ---------------------------------------------------------------------------
// Kernel 1a: transpose+convert proj_w [HID][SDRN] f32 -> Wt [TROWS][HID] bf16
// ---------------------------------------------------------------------------
__global__ __launch_bounds__(256) void transpose_cvt(const float* __restrict__ in,
                                                     __hip_bfloat16* __restrict__ out) {
    __shared__ float tile[32][33];
    int x = blockIdx.x * 32 + threadIdx.x;  // n
    int y = blockIdx.y * 32 + threadIdx.y;  // h
#pragma unroll
    for (int j = 0; j < 32; j += 8)
        tile[threadIdx.y + j][threadIdx.x] = in[(size_t)(y + j) * SDRN + x];
    __syncthreads();
    x = blockIdx.y * 32 + threadIdx.x;      // h
    y = blockIdx.x * 32 + threadIdx.y;      // n
#pragma unroll
    for (int j = 0; j < 32; j += 8)
        out[(size_t)(y + j) * HID + x] = __float2bfloat16(tile[threadIdx.x][threadIdx.y + j]);
}

// Kernel 1b: zero the padding row (row PADID = 4096 B)
__global__ void zero_pad_row(__hip_bfloat16* __restrict__ Wt) {
    u32x4 z = {0u, 0u, 0u, 0u};
    *((u32x4*)(Wt + (size_t)PADID * HID) + threadIdx.x) = z;  // 256 x 16 B
}

// ---------------------------------------------------------------------------
// Pass 1: one 512-wide h-slice per wave's token; slice pinned to XCD pair via
// blockIdx&7 so each XCD-pair's 2 MB table slice stays L2-resident.
// Branchless: unique ids compacted + padded with zero-row id to a multiple
// of 4; rows fetched via SGPR base (readlane) with 4 loads in flight.
// XBF: write pre-LN x as bf16 (to ws) else f32 (to d_out).
// ---------------------------------------------------------------------------
template <bool XBF>
__global__ __launch_bounds__(256) void sdr_gather_p1(
    const int* __restrict__ ids, const __hip_bfloat16* __restrict__ Wt,
    void* __restrict__ xout, float2* __restrict__ partials) {
    const int b     = blockIdx.x;
    const int sub   = b & 1;
    const int slice = (b & 7) >> 1;                 // 4 slices x 2 XCDs
    const int tg    = ((b >> 3) << 1) | sub;        // token group (4 tokens)
    const int wave  = threadIdx.x >> 6;
    const int lane  = threadIdx.x & 63;
    const int token = tg * 4 + wave;

    __shared__ int s_uids[4][44];

    // load ids + dedupe in-register
    int myid = (lane < WW) ? ids[(size_t)token * WW + lane] : 0;
    int keep = (lane < WW) ? 1 : 0;
#pragma unroll
    for (int j = 0; j < WW; ++j) {
        const int idj = __shfl(myid, j);
        if (j < lane && lane < WW && idj == myid) keep = 0;
    }
    const unsigned long long km = __ballot(keep);
    const int nkeep = __popcll(km);
    const int nk4   = (nkeep + 3) & ~3;             // pad to multiple of 4 (<=44)
    if (keep) {
        const int rank = __popcll(km & ((1ull << lane) - 1ull));
        s_uids[wave][rank] = myid;
    }
    if (lane >= nkeep && lane < nk4) s_uids[wave][lane] = PADID;
    const int cid = s_uids[wave][lane < 44 ? lane : 0];

    f32x2 a0 = {0.f, 0.f}, a1 = {0.f, 0.f}, a2 = {0.f, 0.f}, a3 = {0.f, 0.f};
    const int lofs = slice * SLICE_H + lane * 8;    // element offset in a row

#define ACC8(u)                                                                 \
    { f32x2 t;                                                                  \
      t.x = __uint_as_float((u).x << 16); t.y = __uint_as_float((u).x & 0xffff0000u); a0 += t; \
      t.x = __uint_as_float((u).y << 16); t.y = __uint_as_float((u).y & 0xffff0000u); a1 += t; \
      t.x = __uint_as_float((u).z << 16); t.y = __uint_as_float((u).z & 0xffff0000u); a2 += t; \
      t.x = __uint_as_float((u).w << 16); t.y = __uint_as_float((u).w & 0xffff0000u); a3 += t; }

    for (int i = 0; i < nk4; i += 4) {
        const int id0 = __builtin_amdgcn_readlane(cid, i);
        const int id1 = __builtin_amdgcn_readlane(cid, i + 1);
        const int id2 = __builtin_amdgcn_readlane(cid, i + 2);
        const int id3 = __builtin_amdgcn_readlane(cid, i + 3);
        const u32x4 u0 = *(const u32x4*)((const unsigned int*)(Wt + (size_t)id0 * HID + lofs));
        const u32x4 u1 = *(const u32x4*)((const unsigned int*)(Wt + (size_t)id1 * HID + lofs));
        const u32x4 u2 = *(const u32x4*)((const unsigned int*)(Wt + (size_t)id2 * HID + lofs));
        const u32x4 u3 = *(const u32x4*)((const unsigned int*)(Wt + (size_t)id3 * HID + lofs));
        ACC8(u0); ACC8(u1); ACC8(u2); ACC8(u3);
    }
#undef ACC8

    // per-wave partial (sum, sumsq) for this slice
    float s  = a0.x + a0.y + a1.x + a1.y + a2.x + a2.y + a3.x + a3.y;
    float s2 = a0.x * a0.x + a0.y * a0.y + a1.x * a1.x + a1.y * a1.y +
               a2.x * a2.x + a2.y * a2.y + a3.x * a3.x + a3.y * a3.y;
#pragma unroll
    for (int off = 1; off < 64; off <<= 1) {
        s  += __shfl_xor(s, off);
        s2 += __shfl_xor(s2, off);
    }
    if (lane == 0) {
        float2 p; p.x = s; p.y = s2;
        partials[(size_t)token * NSLICE + slice] = p;
    }

    if (XBF) {
        u32x4 o;
        o.x = (unsigned)bf16bits(a0.x) | ((unsigned)bf16bits(a0.y) << 16);
        o.y = (unsigned)bf16bits(a1.x) | ((unsigned)bf16bits(a1.y) << 16);
        o.z = (unsigned)bf16bits(a2.x) | ((unsigned)bf16bits(a2.y) << 16);
        o.w = (unsigned)bf16bits(a3.x) | ((unsigned)bf16bits(a3.y) << 16);
        __hip_bfloat16* xb = (__hip_bfloat16*)xout;
        __builtin_nontemporal_store(o, (u32x4*)(xb + (size_t)token * HID + lofs));
    } else {
        float* xf = (float*)xout;
        f32x4 v0; v0.x = a0.x; v0.y = a0.y; v0.z = a1.x; v0.w = a1.y;
        f32x4 v1; v1.x = a2.x; v1.y = a2.y; v1.z = a3.x; v1.w = a3.y;
        f32x4* xr = (f32x4*)(xf + (size_t)token * HID + lofs);
        __builtin_nontemporal_store(v0, xr);
        __builtin_nontemporal_store(v1, xr + 1);
    }
}

// ---------------------------------------------------------------------------
// Pass 2a: x is bf16 in ws -> normalize -> f32 out
// ---------------------------------------------------------------------------
__global__ __launch_bounds__(256) void sdr_ln_p2_bf(
    const __hip_bfloat16* __restrict__ xbf, const float2* __restrict__ partials,
    const float* __restrict__ gamma, const float* __restrict__ beta,
    float* __restrict__ out) {
    const int token = blockIdx.x;
    const int tid   = threadIdx.x;

    float s = 0.f, s2 = 0.f;
#pragma unroll
    for (int j = 0; j < NSLICE; ++j) {
        const float2 p = partials[(size_t)token * NSLICE + j];
        s += p.x; s2 += p.y;
    }
    const float mean = s * (1.0f / HID);
    const float var  = s2 * (1.0f / HID) - mean * mean;
    const float rstd = rsqrtf(var + EPS_LN);

    const u32x4 u = *((const u32x4*)(xbf + (size_t)token * HID) + tid);
    float xv[8];
    xv[0] = __uint_as_float(u.x << 16); xv[1] = __uint_as_float(u.x & 0xffff0000u);
    xv[2] = __uint_as_float(u.y << 16); xv[3] = __uint_as_float(u.y & 0xffff0000u);
    xv[4] = __uint_as_float(u.z << 16); xv[5] = __uint_as_float(u.z & 0xffff0000u);
    xv[6] = __uint_as_float(u.w << 16); xv[7] = __uint_as_float(u.w & 0xffff0000u);

    const f32x4* g4 = (const f32x4*)gamma + tid * 2;
    const f32x4* b4 = (const f32x4*)beta  + tid * 2;
    const f32x4 g0 = g4[0], g1 = g4[1];
    const f32x4 be0 = b4[0], be1 = b4[1];
    f32x4 r0, r1;
    r0.x = (xv[0] - mean) * rstd * g0.x + be0.x;
    r0.y = (xv[1] - mean) * rstd * g0.y + be0.y;
    r0.z = (xv[2] - mean) * rstd * g0.z + be0.z;
    r0.w = (xv[3] - mean) * rstd * g0.w + be0.w;
    r1.x = (xv[4] - mean) * rstd * g1.x + be1.x;
    r1.y = (xv[5] - mean) * rstd * g1.y + be1.y;
    r1.z = (xv[6] - mean) * rstd * g1.z + be1.z;
    r1.w = (xv[7] - mean) * rstd * g1.w + be1.w;
    f32x4* o4 = (f32x4*)(out + (size_t)token * HID) + tid * 2;
    __builtin_nontemporal_store(r0, o4);
    __builtin_nontemporal_store(r1, o4 + 1);
}

// ---------------------------------------------------------------------------
// Pass 2b: x is f32 in d_out -> normalize in place
// ---------------------------------------------------------------------------
__global__ __launch_bounds__(256) void sdr_ln_p2_inplace(
    float* __restrict__ x, const float2* __restrict__ partials,
    const float* __restrict__ gamma, const float* __restrict__ beta) {
    const int token = blockIdx.x;
    const int tid   = threadIdx.x;

    float s = 0.f, s2 = 0.f;
#pragma unroll
    for (int j = 0; j < NSLICE; ++j) {
        const float2 p = partials[(size_t)token * NSLICE + j];
        s += p.x; s2 += p.y;
    }
    const float mean = s * (1.0f / HID);
    const float var  = s2 * (1.0f / HID) - mean * mean;
    const float rstd = rsqrtf(var + EPS_LN);

    float4*       xr = (float4*)(x + (size_t)token * HID) + tid * 2;
    const float4* g4 = (const float4*)gamma + tid * 2;
    const float4* b4 = (const float4*)beta  + tid * 2;
    float4 a = xr[0], bq = xr[1];
    const float4 g0 = g4[0], g1 = g4[1];
    const float4 be0 = b4[0], be1 = b4[1];
    a.x  = (a.x  - mean) * rstd * g0.x + be0.x;
    a.y  = (a.y  - mean) * rstd * g0.y + be0.y;
    a.z  = (a.z  - mean) * rstd * g0.z + be0.z;
    a.w  = (a.w  - mean) * rstd * g0.w + be0.w;
    bq.x = (bq.x - mean) * rstd * g1.x + be1.x;
    bq.y = (bq.y - mean) * rstd * g1.y + be1.y;
    bq.z = (bq.z - mean) * rstd * g1.z + be1.z;
    bq.w = (bq.w - mean) * rstd * g1.w + be1.w;
    xr[0] = a;
    xr[1] = bq;
}

// ---------------------------------------------------------------------------
// Fallback (tiny ws): gather directly from proj_w columns, fused LN.
// ---------------------------------------------------------------------------
__global__ __launch_bounds__(256) void sdr_gather_ln_notr(
    const int* __restrict__ ids, const float* __restrict__ W,
    const float* __restrict__ gamma, const float* __restrict__ beta,
    float* __restrict__ out) {
    const int token = blockIdx.x;
    const int tid   = threadIdx.x;

    __shared__ int   s_ids[WW];
    __shared__ int   s_keep[WW];
    __shared__ float s_red[8];

    if (tid < WW) s_ids[tid] = ids[(size_t)token * WW + tid];
    __syncthreads();
    if (tid < WW) {
        const int v = s_ids[tid];
        int keep = 1;
        for (int j = 0; j < tid; ++j)
            if (s_ids[j] == v) { keep = 0; break; }
        s_keep[tid] = keep;
    }
    __syncthreads();

    float acc[8] = {0.f};
    for (int i = 0; i < WW; ++i) {
        if (!s_keep[i]) continue;
        const int id = s_ids[i];
#pragma unroll
        for (int j = 0; j < 8; ++j) {
            const int h = tid * 8 + j;
            acc[j] += W[(size_t)h * SDRN + id];
        }
    }
    float s = 0.f, s2 = 0.f;
#pragma unroll
    for (int j = 0; j < 8; ++j) { s += acc[j]; s2 += acc[j] * acc[j]; }
#pragma unroll
    for (int off = 1; off < 64; off <<= 1) {
        s  += __shfl_xor(s, off);
        s2 += __shfl_xor(s2, off);
    }
    const int wave = tid >> 6;
    if ((tid & 63) == 0) { s_red[wave] = s; s_red[4 + wave] = s2; }
    __syncthreads();
    const float ts   = s_red[0] + s_red[1] + s_red[2] + s_red[3];
    const float ts2  = s_red[4] + s_red[5] + s_red[6] + s_red[7];
    const float mean = ts * (1.0f / HID);
    const float var  = ts2 * (1.0f / HID) - mean * mean;
    const float rstd = rsqrtf(var + EPS_LN);

#pragma unroll
    for (int j = 0; j < 8; ++j) {
        const int h = tid * 8 + j;
        out[(size_t)token * HID + h] = (acc[j] - mean) * rstd * gamma[h] + beta[h];
    }
}

extern "C" void kernel_launch(void* const* d_in, const int* in_sizes, int n_in,
                              void* d_out, int out_size, void* d_ws, size_t ws_size,
                              hipStream_t stream) {
    const int*   ids    = (const int*)d_in[0];
    const float* proj_w = (const float*)d_in[1];
    const float* gamma  = (const float*)d_in[2];
    const float* beta   = (const float*)d_in[3];
    float*       out    = (float*)d_out;

    const size_t wt_bytes   = (size_t)TROWS * HID * sizeof(__hip_bfloat16);  // ~8.4 MB
    const size_t part_bytes = (size_t)NTOK * NSLICE * sizeof(float2);        // 512 KB
    const size_t xbf_bytes  = (size_t)NTOK * HID * sizeof(__hip_bfloat16);   // 67 MB
    const size_t need_core  = wt_bytes + part_bytes;
    const size_t need_full  = need_core + xbf_bytes;

    if (ws_size >= need_core) {
        __hip_bfloat16* Wt = (__hip_bfloat16*)d_ws;
        float2* partials   = (float2*)((char*)d_ws + wt_bytes);

        dim3 tb(32, 8), tg(SDRN / 32, HID / 32);
        transpose_cvt<<<tg, tb, 0, stream>>>(proj_w, Wt);
        zero_pad_row<<<1, 256, 0, stream>>>(Wt);

        if (ws_size >= need_full) {
            __hip_bfloat16* xbf = (__hip_bfloat16*)((char*)d_ws + need_core);
            sdr_gather_p1<true><<<NTOK, 256, 0, stream>>>(ids, Wt, xbf, partials);
            sdr_ln_p2_bf<<<NTOK, 256, 0, stream>>>(xbf, partials, gamma, beta, out);
        } else {
            sdr_gather_p1<false><<<NTOK, 256, 0, stream>>>(ids, Wt, out, partials);
            sdr_ln_p2_inplace<<<NTOK, 256, 0, stream>>>(out, partials, gamma, beta);
        }
    } else {
        sdr_gather_ln_notr<<<NTOK, 256, 0, stream>>>(ids, proj_w, gamma, beta, out);
    }
}

// Round 10
// 166.812 us; speedup vs baseline: 3.5115x; 1.0009x over previous
//
#include <hip/hip_runtime.h>
#include <hip/hip_bf16.h>

// Problem constants (match reference)
#define BB      4
#define SS      4096
#define WW      41
#define SDRN    2048
#define HID     2048
#define NTOK    (BB * SS)
#define EPS_LN  1e-5f
#define NSLICE  4
#define SLICE_H 512        // HID / NSLICE
#define PADID   SDRN       // index of the all-zeros padding row
#define TROWS   (SDRN + 1) // table rows incl. zero row

typedef float        f32x4 __attribute__((ext_vector_type(4)));
typedef unsigned int u32x4 __attribute__((ext_vector_type(4)));

static __device__ __forceinline__ unsigned short bf16bits(float f) {
    return __builtin_bit_cast(unsigned short, __float2bfloat16(f));
}

// ---------------------------------------------------------------------------
// Kernel 1a: transpose+convert proj_w [HID][SDRN] f32 -> Wt [TROWS][HID] bf16
// ---------------------------------------------------------------------------
__global__ __launch_bounds__(256) void transpose_cvt(const float* __restrict__ in,
                                                     __hip_bfloat16* __restrict__ out) {
    __shared__ float tile[32][33];
    int x = blockIdx.x * 32 + threadIdx.x;  // n
    int y = blockIdx.y * 32 + threadIdx.y;  // h
#pragma unroll
    for (int j = 0; j < 32; j += 8)
        tile[threadIdx.y + j][threadIdx.x] = in[(size_t)(y + j) * SDRN + x];
    __syncthreads();
    x = blockIdx.y * 32 + threadIdx.x;      // h
    y = blockIdx.x * 32 + threadIdx.y;      // n
#pragma unroll
    for (int j = 0; j < 32; j += 8)
        out[(size_t)(y + j) * HID + x] = __float2bfloat16(tile[threadIdx.x][threadIdx.y + j]);
}

// Kernel 1b: zero the padding row (row PADID = 4096 B)
__global__ void zero_pad_row(__hip_bfloat16* __restrict__ Wt) {
    u32x4 z = {0u, 0u, 0u, 0u};
    *((u32x4*)(Wt + (size_t)PADID * HID) + threadIdx.x) = z;  // 256 x 16 B
}

// ---------------------------------------------------------------------------
// Pass 1: one 512-wide h-slice per wave's token; slice pinned to XCD pair via
// blockIdx&7 so each XCD-pair's 2 MB table slice stays L2-resident.
// Branchless: unique ids compacted + padded with zero-row id to a multiple
// of 4; rows fetched via SGPR base (readlane) with 4 loads in flight.
// XBF: write pre-LN x as bf16 (to ws) else f32 (to d_out).
// ---------------------------------------------------------------------------
template <bool XBF>
__global__ __launch_bounds__(256) void sdr_gather_p1(
    const int* __restrict__ ids, const __hip_bfloat16* __restrict__ Wt,
    void* __restrict__ xout, float2* __restrict__ partials) {
    const int b     = blockIdx.x;
    const int sub   = b & 1;
    const int slice = (b & 7) >> 1;                 // 4 slices x 2 XCDs
    const int tg    = ((b >> 3) << 1) | sub;        // token group (4 tokens)
    const int wave  = threadIdx.x >> 6;
    const int lane  = threadIdx.x & 63;
    const int token = tg * 4 + wave;

    __shared__ int s_uids[4][44];

    // load ids + dedupe in-register
    int myid = (lane < WW) ? ids[(size_t)token * WW + lane] : 0;
    int keep = (lane < WW) ? 1 : 0;
#pragma unroll
    for (int j = 0; j < WW; ++j) {
        const int idj = __shfl(myid, j);
        if (j < lane && lane < WW && idj == myid) keep = 0;
    }
    const unsigned long long km = __ballot(keep);
    const int nkeep = __popcll(km);
    const int nk4   = (nkeep + 3) & ~3;             // pad to multiple of 4 (<=44)
    if (keep) {
        const int rank = __popcll(km & ((1ull << lane) - 1ull));
        s_uids[wave][rank] = myid;
    }
    if (lane >= nkeep && lane < nk4) s_uids[wave][lane] = PADID;
    const int cid = s_uids[wave][lane < 44 ? lane : 0];

    typedef float f32x2 __attribute__((ext_vector_type(2)));
    f32x2 a0 = {0.f, 0.f}, a1 = {0.f, 0.f}, a2 = {0.f, 0.f}, a3 = {0.f, 0.f};
    const int lofs = slice * SLICE_H + lane * 8;    // element offset in a row

#define ACC8(u)                                                                 \
    { f32x2 t;                                                                  \
      t.x = __uint_as_float((u).x << 16); t.y = __uint_as_float((u).x & 0xffff0000u); a0 += t; \
      t.x = __uint_as_float((u).y << 16); t.y = __uint_as_float((u).y & 0xffff0000u); a1 += t; \
      t.x = __uint_as_float((u).z << 16); t.y = __uint_as_float((u).z & 0xffff0000u); a2 += t; \
      t.x = __uint_as_float((u).w << 16); t.y = __uint_as_float((u).w & 0xffff0000u); a3 += t; }

    for (int i = 0; i < nk4; i += 4) {
        const int id0 = __builtin_amdgcn_readlane(cid, i);
        const int id1 = __builtin_amdgcn_readlane(cid, i + 1);
        const int id2 = __builtin_amdgcn_readlane(cid, i + 2);
        const int id3 = __builtin_amdgcn_readlane(cid, i + 3);
        const u32x4 u0 = *(const u32x4*)((const unsigned int*)Wt + (size_t)id0 * (HID / 2) + (lofs >> 1));
        const u32x4 u1 = *(const u32x4*)((const unsigned int*)Wt + (size_t)id1 * (HID / 2) + (lofs >> 1));
        const u32x4 u2 = *(const u32x4*)((const unsigned int*)Wt + (size_t)id2 * (HID / 2) + (lofs >> 1));
        const u32x4 u3 = *(const u32x4*)((const unsigned int*)Wt + (size_t)id3 * (HID / 2) + (lofs >> 1));
        ACC8(u0); ACC8(u1); ACC8(u2); ACC8(u3);
    }
#undef ACC8

    // per-wave partial (sum, sumsq) for this slice
    float s  = a0.x + a0.y + a1.x + a1.y + a2.x + a2.y + a3.x + a3.y;
    float s2 = a0.x * a0.x + a0.y * a0.y + a1.x * a1.x + a1.y * a1.y +
               a2.x * a2.x + a2.y * a2.y + a3.x * a3.x + a3.y * a3.y;
#pragma unroll
    for (int off = 1; off < 64; off <<= 1) {
        s  += __shfl_xor(s, off);
        s2 += __shfl_xor(s2, off);
    }
    if (lane == 0) {
        float2 p; p.x = s; p.y = s2;
        partials[(size_t)token * NSLICE + slice] = p;
    }

    if (XBF) {
        u32x4 o;
        o.x = (unsigned)bf16bits(a0.x) | ((unsigned)bf16bits(a0.y) << 16);
        o.y = (unsigned)bf16bits(a1.x) | ((unsigned)bf16bits(a1.y) << 16);
        o.z = (unsigned)bf16bits(a2.x) | ((unsigned)bf16bits(a2.y) << 16);
        o.w = (unsigned)bf16bits(a3.x) | ((unsigned)bf16bits(a3.y) << 16);
        __hip_bfloat16* xb = (__hip_bfloat16*)xout;
        __builtin_nontemporal_store(o, (u32x4*)(xb + (size_t)token * HID + lofs));
    } else {
        float* xf = (float*)xout;
        f32x4 v0; v0.x = a0.x; v0.y = a0.y; v0.z = a1.x; v0.w = a1.y;
        f32x4 v1; v1.x = a2.x; v1.y = a2.y; v1.z = a3.x; v1.w = a3.y;
        f32x4* xr = (f32x4*)(xf + (size_t)token * HID + lofs);
        __builtin_nontemporal_store(v0, xr);
        __builtin_nontemporal_store(v1, xr + 1);
    }
}

// ---------------------------------------------------------------------------
// Pass 2a: x is bf16 in ws -> normalize -> f32 out
// ---------------------------------------------------------------------------
__global__ __launch_bounds__(256) void sdr_ln_p2_bf(
    const __hip_bfloat16* __restrict__ xbf, const float2* __restrict__ partials,
    const float* __restrict__ gamma, const float* __restrict__ beta,
    float* __restrict__ out) {
    const int token = blockIdx.x;
    const int tid   = threadIdx.x;

    float s = 0.f, s2 = 0.f;
#pragma unroll
    for (int j = 0; j < NSLICE; ++j) {
        const float2 p = partials[(size_t)token * NSLICE + j];
        s += p.x; s2 += p.y;
    }
    const float mean = s * (1.0f / HID);
    const float var  = s2 * (1.0f / HID) - mean * mean;
    const float rstd = rsqrtf(var + EPS_LN);

    const u32x4 u = *((const u32x4*)(xbf + (size_t)token * HID) + tid);
    float xv[8];
    xv[0] = __uint_as_float(u.x << 16); xv[1] = __uint_as_float(u.x & 0xffff0000u);
    xv[2] = __uint_as_float(u.y << 16); xv[3] = __uint_as_float(u.y & 0xffff0000u);
    xv[4] = __uint_as_float(u.z << 16); xv[5] = __uint_as_float(u.z & 0xffff0000u);
    xv[6] = __uint_as_float(u.w << 16); xv[7] = __uint_as_float(u.w & 0xffff0000u);

    const f32x4* g4 = (const f32x4*)gamma + tid * 2;
    const f32x4* b4 = (const f32x4*)beta  + tid * 2;
    const f32x4 g0 = g4[0], g1 = g4[1];
    const f32x4 be0 = b4[0], be1 = b4[1];
    f32x4 r0, r1;
    r0.x = (xv[0] - mean) * rstd * g0.x + be0.x;
    r0.y = (xv[1] - mean) * rstd * g0.y + be0.y;
    r0.z = (xv[2] - mean) * rstd * g0.z + be0.z;
    r0.w = (xv[3] - mean) * rstd * g0.w + be0.w;
    r1.x = (xv[4] - mean) * rstd * g1.x + be1.x;
    r1.y = (xv[5] - mean) * rstd * g1.y + be1.y;
    r1.z = (xv[6] - mean) * rstd * g1.z + be1.z;
    r1.w = (xv[7] - mean) * rstd * g1.w + be1.w;
    f32x4* o4 = (f32x4*)(out + (size_t)token * HID) + tid * 2;
    __builtin_nontemporal_store(r0, o4);
    __builtin_nontemporal_store(r1, o4 + 1);
}

// ---------------------------------------------------------------------------
// Pass 2b: x is f32 in d_out -> normalize in place
// ---------------------------------------------------------------------------
__global__ __launch_bounds__(256) void sdr_ln_p2_inplace(
    float* __restrict__ x, const float2* __restrict__ partials,
    const float* __restrict__ gamma, const float* __restrict__ beta) {
    const int token = blockIdx.x;
    const int tid   = threadIdx.x;

    float s = 0.f, s2 = 0.f;
#pragma unroll
    for (int j = 0; j < NSLICE; ++j) {
        const float2 p = partials[(size_t)token * NSLICE + j];
        s += p.x; s2 += p.y;
    }
    const float mean = s * (1.0f / HID);
    const float var  = s2 * (1.0f / HID) - mean * mean;
    const float rstd = rsqrtf(var + EPS_LN);

    float4*       xr = (float4*)(x + (size_t)token * HID) + tid * 2;
    const float4* g4 = (const float4*)gamma + tid * 2;
    const float4* b4 = (const float4*)beta  + tid * 2;
    float4 a = xr[0], bq = xr[1];
    const float4 g0 = g4[0], g1 = g4[1];
    const float4 be0 = b4[0], be1 = b4[1];
    a.x  = (a.x  - mean) * rstd * g0.x + be0.x;
    a.y  = (a.y  - mean) * rstd * g0.y + be0.y;
    a.z  = (a.z  - mean) * rstd * g0.z + be0.z;
    a.w  = (a.w  - mean) * rstd * g0.w + be0.w;
    bq.x = (bq.x - mean) * rstd * g1.x + be1.x;
    bq.y = (bq.y - mean) * rstd * g1.y + be1.y;
    bq.z = (bq.z - mean) * rstd * g1.z + be1.z;
    bq.w = (bq.w - mean) * rstd * g1.w + be1.w;
    xr[0] = a;
    xr[1] = bq;
}

// ---------------------------------------------------------------------------
// Fallback (tiny ws): gather directly from proj_w columns, fused LN.
// ---------------------------------------------------------------------------
__global__ __launch_bounds__(256) void sdr_gather_ln_notr(
    const int* __restrict__ ids, const float* __restrict__ W,
    const float* __restrict__ gamma, const float* __restrict__ beta,
    float* __restrict__ out) {
    const int token = blockIdx.x;
    const int tid   = threadIdx.x;

    __shared__ int   s_ids[WW];
    __shared__ int   s_keep[WW];
    __shared__ float s_red[8];

    if (tid < WW) s_ids[tid] = ids[(size_t)token * WW + tid];
    __syncthreads();
    if (tid < WW) {
        const int v = s_ids[tid];
        int keep = 1;
        for (int j = 0; j < tid; ++j)
            if (s_ids[j] == v) { keep = 0; break; }
        s_keep[tid] = keep;
    }
    __syncthreads();

    float acc[8] = {0.f};
    for (int i = 0; i < WW; ++i) {
        if (!s_keep[i]) continue;
        const int id = s_ids[i];
#pragma unroll
        for (int j = 0; j < 8; ++j) {
            const int h = tid * 8 + j;
            acc[j] += W[(size_t)h * SDRN + id];
        }
    }
    float s = 0.f, s2 = 0.f;
#pragma unroll
    for (int j = 0; j < 8; ++j) { s += acc[j]; s2 += acc[j] * acc[j]; }
#pragma unroll
    for (int off = 1; off < 64; off <<= 1) {
        s  += __shfl_xor(s, off);
        s2 += __shfl_xor(s2, off);
    }
    const int wave = tid >> 6;
    if ((tid & 63) == 0) { s_red[wave] = s; s_red[4 + wave] = s2; }
    __syncthreads();
    const float ts   = s_red[0] + s_red[1] + s_red[2] + s_red[3];
    const float ts2  = s_red[4] + s_red[5] + s_red[6] + s_red[7];
    const float mean = ts * (1.0f / HID);
    const float var  = ts2 * (1.0f / HID) - mean * mean;
    const float rstd = rsqrtf(var + EPS_LN);

#pragma unroll
    for (int j = 0; j < 8; ++j) {
        const int h = tid * 8 + j;
        out[(size_t)token * HID + h] = (acc[j] - mean) * rstd * gamma[h] + beta[h];
    }
}

extern "C" void kernel_launch(void* const* d_in, const int* in_sizes, int n_in,
                              void* d_out, int out_size, void* d_ws, size_t ws_size,
                              hipStream_t stream) {
    const int*   ids    = (const int*)d_in[0];
    const float* proj_w = (const float*)d_in[1];
    const float* gamma  = (const float*)d_in[2];
    const float* beta   = (const float*)d_in[3];
    float*       out    = (float*)d_out;

    const size_t wt_bytes   = (size_t)TROWS * HID * sizeof(__hip_bfloat16);  // ~8.4 MB
    const size_t part_bytes = (size_t)NTOK * NSLICE * sizeof(float2);        // 512 KB
    const size_t xbf_bytes  = (size_t)NTOK * HID * sizeof(__hip_bfloat16);   // 67 MB
    const size_t need_core  = wt_bytes + part_bytes;
    const size_t need_full  = need_core + xbf_bytes;

    if (ws_size >= need_core) {
        __hip_bfloat16* Wt = (__hip_bfloat16*)d_ws;
        float2* partials   = (float2*)((char*)d_ws + wt_bytes);

        dim3 tb(32, 8), tg(SDRN / 32, HID / 32);
        transpose_cvt<<<tg, tb, 0, stream>>>(proj_w, Wt);
        zero_pad_row<<<1, 256, 0, stream>>>(Wt);

        if (ws_size >= need_full) {
            __hip_bfloat16* xbf = (__hip_bfloat16*)((char*)d_ws + need_core);
            sdr_gather_p1<true><<<NTOK, 256, 0, stream>>>(ids, Wt, xbf, partials);
            sdr_ln_p2_bf<<<NTOK, 256, 0, stream>>>(xbf, partials, gamma, beta, out);
        } else {
            sdr_gather_p1<false><<<NTOK, 256, 0, stream>>>(ids, Wt, out, partials);
            sdr_ln_p2_inplace<<<NTOK, 256, 0, stream>>>(out, partials, gamma, beta);
        }
    } else {
        sdr_gather_ln_notr<<<NTOK, 256, 0, stream>>>(ids, proj_w, gamma, beta, out);
    }
}

// Round 12
// 166.508 us; speedup vs baseline: 3.5179x; 1.0018x over previous
//
#include <hip/hip_runtime.h>
#include <hip/hip_bf16.h>

// Problem constants (match reference)
#define BB      4
#define SS      4096
#define WW      41
#define SDRN    2048
#define HID     2048
#define NTOK    (BB * SS)
#define EPS_LN  1e-5f
#define NSLICE  4
#define SLICE_H 512        // HID / NSLICE
#define PADID   SDRN       // index of the all-zeros padding row
#define TROWS   (SDRN + 1) // table rows incl. zero row
#define UIDS    48         // padded id-list stride (ints)

typedef float        f32x4 __attribute__((ext_vector_type(4)));
typedef unsigned int u32x4 __attribute__((ext_vector_type(4)));

static __device__ __forceinline__ unsigned short bf16bits(float f) {
    return __builtin_bit_cast(unsigned short, __float2bfloat16(f));
}

// ---------------------------------------------------------------------------
// Kernel 1a: transpose+convert proj_w [HID][SDRN] f32 -> Wt [TROWS][HID] bf16
// ---------------------------------------------------------------------------
__global__ __launch_bounds__(256) void transpose_cvt(const float* __restrict__ in,
                                                     __hip_bfloat16* __restrict__ out) {
    __shared__ float tile[32][33];
    int x = blockIdx.x * 32 + threadIdx.x;  // n
    int y = blockIdx.y * 32 + threadIdx.y;  // h
#pragma unroll
    for (int j = 0; j < 32; j += 8)
        tile[threadIdx.y + j][threadIdx.x] = in[(size_t)(y + j) * SDRN + x];
    __syncthreads();
    x = blockIdx.y * 32 + threadIdx.x;      // h
    y = blockIdx.x * 32 + threadIdx.y;      // n
#pragma unroll
    for (int j = 0; j < 32; j += 8)
        out[(size_t)(y + j) * HID + x] = __float2bfloat16(tile[threadIdx.x][threadIdx.y + j]);
}

// Kernel 1b: zero the padding row (row PADID = 4096 B)
__global__ void zero_pad_row(__hip_bfloat16* __restrict__ Wt) {
    u32x4 z = {0u, 0u, 0u, 0u};
    *((u32x4*)(Wt + (size_t)PADID * HID) + threadIdx.x) = z;  // 256 x 16 B
}

// ---------------------------------------------------------------------------
// Kernel 1c: per-token dedupe (hoisted). One wave per token; compacted unique
// ids, padded with PADID to 44 entries; count (rounded up to x4) in ucnt.
// Pure integer dataflow; dedupe logic identical to the R10-proven inline one.
// ---------------------------------------------------------------------------
__global__ __launch_bounds__(256) void dedup_k(const int* __restrict__ ids,
                                               int* __restrict__ uidp,
                                               int* __restrict__ ucnt) {
    const int wave  = threadIdx.x >> 6;
    const int lane  = threadIdx.x & 63;
    const int token = blockIdx.x * 4 + wave;

    int myid = (lane < WW) ? ids[(size_t)token * WW + lane] : 0;
    int keep = (lane < WW) ? 1 : 0;
#pragma unroll
    for (int j = 0; j < WW; ++j) {
        const int idj = __shfl(myid, j);
        if (j < lane && lane < WW && idj == myid) keep = 0;
    }
    const unsigned long long km = __ballot(keep);
    const int nkeep = __popcll(km);
    const int nk4   = (nkeep + 3) & ~3;             // <= 44
    int* dst = uidp + (size_t)token * UIDS;
    if (keep) {
        const int rank = __popcll(km & ((1ull << lane) - 1ull));
        dst[rank] = myid;
    }
    if (lane >= nkeep && lane < 44) dst[lane] = PADID;
    if (lane == 0) ucnt[token] = nk4;
}

// ---------------------------------------------------------------------------
// Pass 1: one 512-wide h-slice per wave's token; slice pinned to XCD pair via
// blockIdx&7 so each XCD-pair's 2 MB table slice stays L2-resident.
// Inner loop / epilogue: byte-for-byte the R10-proven f32 unpack+pk_add path.
// PRED: read pre-deduped id list (flat load) vs R10-proven inline dedupe.
// XBF: write pre-LN x as bf16 (to ws) else f32 (to d_out).
// ---------------------------------------------------------------------------
template <bool PRED, bool XBF>
__global__ __launch_bounds__(256) void sdr_gather_p1(
    const int* __restrict__ ids, const int* __restrict__ uidp,
    const int* __restrict__ ucnt, const __hip_bfloat16* __restrict__ Wt,
    void* __restrict__ xout, float2* __restrict__ partials) {
    const int b     = blockIdx.x;
    const int sub   = b & 1;
    const int slice = (b & 7) >> 1;                 // 4 slices x 2 XCDs
    const int tg    = ((b >> 3) << 1) | sub;        // token group (4 tokens)
    const int wave  = threadIdx.x >> 6;
    const int lane  = threadIdx.x & 63;
    const int token = tg * 4 + wave;

    int cid, nk4;
    if (PRED) {
        cid = uidp[(size_t)token * UIDS + (lane < 44 ? lane : 0)];
        nk4 = __builtin_amdgcn_readfirstlane(ucnt[token]);
    } else {
        __shared__ int s_uids[4][44];
        int myid = (lane < WW) ? ids[(size_t)token * WW + lane] : 0;
        int keep = (lane < WW) ? 1 : 0;
#pragma unroll
        for (int j = 0; j < WW; ++j) {
            const int idj = __shfl(myid, j);
            if (j < lane && lane < WW && idj == myid) keep = 0;
        }
        const unsigned long long km = __ballot(keep);
        const int nkeep = __popcll(km);
        nk4 = (nkeep + 3) & ~3;
        if (keep) {
            const int rank = __popcll(km & ((1ull << lane) - 1ull));
            s_uids[wave][rank] = myid;
        }
        if (lane >= nkeep && lane < nk4) s_uids[wave][lane] = PADID;
        cid = s_uids[wave][lane < 44 ? lane : 0];
    }

    typedef float f32x2 __attribute__((ext_vector_type(2)));
    f32x2 a0 = {0.f, 0.f}, a1 = {0.f, 0.f}, a2 = {0.f, 0.f}, a3 = {0.f, 0.f};
    const int lofs = slice * SLICE_H + lane * 8;    // element offset in a row

#define ACC8(u)                                                                 \
    { f32x2 t;                                                                  \
      t.x = __uint_as_float((u).x << 16); t.y = __uint_as_float((u).x & 0xffff0000u); a0 += t; \
      t.x = __uint_as_float((u).y << 16); t.y = __uint_as_float((u).y & 0xffff0000u); a1 += t; \
      t.x = __uint_as_float((u).z << 16); t.y = __uint_as_float((u).z & 0xffff0000u); a2 += t; \
      t.x = __uint_as_float((u).w << 16); t.y = __uint_as_float((u).w & 0xffff0000u); a3 += t; }

    for (int i = 0; i < nk4; i += 4) {
        const int id0 = __builtin_amdgcn_readlane(cid, i);
        const int id1 = __builtin_amdgcn_readlane(cid, i + 1);
        const int id2 = __builtin_amdgcn_readlane(cid, i + 2);
        const int id3 = __builtin_amdgcn_readlane(cid, i + 3);
        const u32x4 u0 = *(const u32x4*)((const unsigned int*)Wt + (size_t)id0 * (HID / 2) + (lofs >> 1));
        const u32x4 u1 = *(const u32x4*)((const unsigned int*)Wt + (size_t)id1 * (HID / 2) + (lofs >> 1));
        const u32x4 u2 = *(const u32x4*)((const unsigned int*)Wt + (size_t)id2 * (HID / 2) + (lofs >> 1));
        const u32x4 u3 = *(const u32x4*)((const unsigned int*)Wt + (size_t)id3 * (HID / 2) + (lofs >> 1));
        ACC8(u0); ACC8(u1); ACC8(u2); ACC8(u3);
    }
#undef ACC8

    // per-wave partial (sum, sumsq) for this slice
    float s  = a0.x + a0.y + a1.x + a1.y + a2.x + a2.y + a3.x + a3.y;
    float s2 = a0.x * a0.x + a0.y * a0.y + a1.x * a1.x + a1.y * a1.y +
               a2.x * a2.x + a2.y * a2.y + a3.x * a3.x + a3.y * a3.y;
#pragma unroll
    for (int off = 1; off < 64; off <<= 1) {
        s  += __shfl_xor(s, off);
        s2 += __shfl_xor(s2, off);
    }
    if (lane == 0) {
        float2 p; p.x = s; p.y = s2;
        partials[(size_t)token * NSLICE + slice] = p;
    }

    if (XBF) {
        u32x4 o;
        o.x = (unsigned)bf16bits(a0.x) | ((unsigned)bf16bits(a0.y) << 16);
        o.y = (unsigned)bf16bits(a1.x) | ((unsigned)bf16bits(a1.y) << 16);
        o.z = (unsigned)bf16bits(a2.x) | ((unsigned)bf16bits(a2.y) << 16);
        o.w = (unsigned)bf16bits(a3.x) | ((unsigned)bf16bits(a3.y) << 16);
        __hip_bfloat16* xb = (__hip_bfloat16*)xout;
        __builtin_nontemporal_store(o, (u32x4*)(xb + (size_t)token * HID + lofs));
    } else {
        float* xf = (float*)xout;
        f32x4 v0; v0.x = a0.x; v0.y = a0.y; v0.z = a1.x; v0.w = a1.y;
        f32x4 v1; v1.x = a2.x; v1.y = a2.y; v1.z = a3.x; v1.w = a3.y;
        f32x4* xr = (f32x4*)(xf + (size_t)token * HID + lofs);
        __builtin_nontemporal_store(v0, xr);
        __builtin_nontemporal_store(v1, xr + 1);
    }
}

// ---------------------------------------------------------------------------
// Pass 2a: x is bf16 in ws -> normalize -> f32 out
// ---------------------------------------------------------------------------
__global__ __launch_bounds__(256) void sdr_ln_p2_bf(
    const __hip_bfloat16* __restrict__ xbf, const float2* __restrict__ partials,
    const float* __restrict__ gamma, const float* __restrict__ beta,
    float* __restrict__ out) {
    const int token = blockIdx.x;
    const int tid   = threadIdx.x;

    float s = 0.f, s2 = 0.f;
#pragma unroll
    for (int j = 0; j < NSLICE; ++j) {
        const float2 p = partials[(size_t)token * NSLICE + j];
        s += p.x; s2 += p.y;
    }
    const float mean = s * (1.0f / HID);
    const float var  = s2 * (1.0f / HID) - mean * mean;
    const float rstd = rsqrtf(var + EPS_LN);

    const u32x4 u = *((const u32x4*)(xbf + (size_t)token * HID) + tid);
    float xv[8];
    xv[0] = __uint_as_float(u.x << 16); xv[1] = __uint_as_float(u.x & 0xffff0000u);
    xv[2] = __uint_as_float(u.y << 16); xv[3] = __uint_as_float(u.y & 0xffff0000u);
    xv[4] = __uint_as_float(u.z << 16); xv[5] = __uint_as_float(u.z & 0xffff0000u);
    xv[6] = __uint_as_float(u.w << 16); xv[7] = __uint_as_float(u.w & 0xffff0000u);

    const f32x4* g4 = (const f32x4*)gamma + tid * 2;
    const f32x4* b4 = (const f32x4*)beta  + tid * 2;
    const f32x4 g0 = g4[0], g1 = g4[1];
    const f32x4 be0 = b4[0], be1 = b4[1];
    f32x4 r0, r1;
    r0.x = (xv[0] - mean) * rstd * g0.x + be0.x;
    r0.y = (xv[1] - mean) * rstd * g0.y + be0.y;
    r0.z = (xv[2] - mean) * rstd * g0.z + be0.z;
    r0.w = (xv[3] - mean) * rstd * g0.w + be0.w;
    r1.x = (xv[4] - mean) * rstd * g1.x + be1.x;
    r1.y = (xv[5] - mean) * rstd * g1.y + be1.y;
    r1.z = (xv[6] - mean) * rstd * g1.z + be1.z;
    r1.w = (xv[7] - mean) * rstd * g1.w + be1.w;
    f32x4* o4 = (f32x4*)(out + (size_t)token * HID) + tid * 2;
    __builtin_nontemporal_store(r0, o4);
    __builtin_nontemporal_store(r1, o4 + 1);
}

// ---------------------------------------------------------------------------
// Pass 2b: x is f32 in d_out -> normalize in place
// ---------------------------------------------------------------------------
__global__ __launch_bounds__(256) void sdr_ln_p2_inplace(
    float* __restrict__ x, const float2* __restrict__ partials,
    const float* __restrict__ gamma, const float* __restrict__ beta) {
    const int token = blockIdx.x;
    const int tid   = threadIdx.x;

    float s = 0.f, s2 = 0.f;
#pragma unroll
    for (int j = 0; j < NSLICE; ++j) {
        const float2 p = partials[(size_t)token * NSLICE + j];
        s += p.x; s2 += p.y;
    }
    const float mean = s * (1.0f / HID);
    const float var  = s2 * (1.0f / HID) - mean * mean;
    const float rstd = rsqrtf(var + EPS_LN);

    float4*       xr = (float4*)(x + (size_t)token * HID) + tid * 2;
    const float4* g4 = (const float4*)gamma + tid * 2;
    const float4* b4 = (const float4*)beta  + tid * 2;
    float4 a = xr[0], bq = xr[1];
    const float4 g0 = g4[0], g1 = g4[1];
    const float4 be0 = b4[0], be1 = b4[1];
    a.x  = (a.x  - mean) * rstd * g0.x + be0.x;
    a.y  = (a.y  - mean) * rstd * g0.y + be0.y;
    a.z  = (a.z  - mean) * rstd * g0.z + be0.z;
    a.w  = (a.w  - mean) * rstd * g0.w + be0.w;
    bq.x = (bq.x - mean) * rstd * g1.x + be1.x;
    bq.y = (bq.y - mean) * rstd * g1.y + be1.y;
    bq.z = (bq.z - mean) * rstd * g1.z + be1.z;
    bq.w = (bq.w - mean) * rstd * g1.w + be1.w;
    xr[0] = a;
    xr[1] = bq;
}

// ---------------------------------------------------------------------------
// Fallback (tiny ws): gather directly from proj_w columns, fused LN.
// ---------------------------------------------------------------------------
__global__ __launch_bounds__(256) void sdr_gather_ln_notr(
    const int* __restrict__ ids, const float* __restrict__ W,
    const float* __restrict__ gamma, const float* __restrict__ beta,
    float* __restrict__ out) {
    const int token = blockIdx.x;
    const int tid   = threadIdx.x;

    __shared__ int   s_ids[WW];
    __shared__ int   s_keep[WW];
    __shared__ float s_red[8];

    if (tid < WW) s_ids[tid] = ids[(size_t)token * WW + tid];
    __syncthreads();
    if (tid < WW) {
        const int v = s_ids[tid];
        int keep = 1;
        for (int j = 0; j < tid; ++j)
            if (s_ids[j] == v) { keep = 0; break; }
        s_keep[tid] = keep;
    }
    __syncthreads();

    float acc[8] = {0.f};
    for (int i = 0; i < WW; ++i) {
        if (!s_keep[i]) continue;
        const int id = s_ids[i];
#pragma unroll
        for (int j = 0; j < 8; ++j) {
            const int h = tid * 8 + j;
            acc[j] += W[(size_t)h * SDRN + id];
        }
    }
    float s = 0.f, s2 = 0.f;
#pragma unroll
    for (int j = 0; j < 8; ++j) { s += acc[j]; s2 += acc[j] * acc[j]; }
#pragma unroll
    for (int off = 1; off < 64; off <<= 1) {
        s  += __shfl_xor(s, off);
        s2 += __shfl_xor(s2, off);
    }
    const int wave = tid >> 6;
    if ((tid & 63) == 0) { s_red[wave] = s; s_red[4 + wave] = s2; }
    __syncthreads();
    const float ts   = s_red[0] + s_red[1] + s_red[2] + s_red[3];
    const float ts2  = s_red[4] + s_red[5] + s_red[6] + s_red[7];
    const float mean = ts * (1.0f / HID);
    const float var  = ts2 * (1.0f / HID) - mean * mean;
    const float rstd = rsqrtf(var + EPS_LN);

#pragma unroll
    for (int j = 0; j < 8; ++j) {
        const int h = tid * 8 + j;
        out[(size_t)token * HID + h] = (acc[j] - mean) * rstd * gamma[h] + beta[h];
    }
}

extern "C" void kernel_launch(void* const* d_in, const int* in_sizes, int n_in,
                              void* d_out, int out_size, void* d_ws, size_t ws_size,
                              hipStream_t stream) {
    const int*   ids    = (const int*)d_in[0];
    const float* proj_w = (const float*)d_in[1];
    const float* gamma  = (const float*)d_in[2];
    const float* beta   = (const float*)d_in[3];
    float*       out    = (float*)d_out;

    const size_t wt_bytes   = (size_t)TROWS * HID * sizeof(__hip_bfloat16);  // ~8.4 MB
    const size_t part_bytes = (size_t)NTOK * NSLICE * sizeof(float2);        // 512 KB
    const size_t uid_bytes  = (size_t)NTOK * UIDS * sizeof(int);             // 3 MB
    const size_t cnt_bytes  = (size_t)NTOK * sizeof(int);                    // 64 KB
    const size_t xbf_bytes  = (size_t)NTOK * HID * sizeof(__hip_bfloat16);   // 67 MB

    const size_t off_part = wt_bytes;
    const size_t off_uid  = off_part + part_bytes;
    const size_t off_cnt  = off_uid + uid_bytes;
    const size_t off_xh_A = off_cnt + cnt_bytes;                 // full layout
    const size_t off_xh_B = off_part + part_bytes;               // no-dedupe layout

    const size_t need_A = off_xh_A + xbf_bytes;   // ~79 MB
    const size_t need_B = off_xh_B + xbf_bytes;   // ~76 MB
    const size_t need_C = wt_bytes + part_bytes;  // ~9 MB

    if (ws_size >= need_C) {
        __hip_bfloat16* Wt = (__hip_bfloat16*)d_ws;
        float2* partials   = (float2*)((char*)d_ws + off_part);

        dim3 tb(32, 8), tg(SDRN / 32, HID / 32);
        transpose_cvt<<<tg, tb, 0, stream>>>(proj_w, Wt);
        zero_pad_row<<<1, 256, 0, stream>>>(Wt);

        if (ws_size >= need_A) {
            int* uidp           = (int*)((char*)d_ws + off_uid);
            int* ucnt           = (int*)((char*)d_ws + off_cnt);
            __hip_bfloat16* xbf = (__hip_bfloat16*)((char*)d_ws + off_xh_A);
            dedup_k<<<NTOK / 4, 256, 0, stream>>>(ids, uidp, ucnt);
            sdr_gather_p1<true, true><<<NTOK, 256, 0, stream>>>(
                ids, uidp, ucnt, Wt, xbf, partials);
            sdr_ln_p2_bf<<<NTOK, 256, 0, stream>>>(xbf, partials, gamma, beta, out);
        } else if (ws_size >= need_B) {
            __hip_bfloat16* xbf = (__hip_bfloat16*)((char*)d_ws + off_xh_B);
            sdr_gather_p1<false, true><<<NTOK, 256, 0, stream>>>(
                ids, nullptr, nullptr, Wt, xbf, partials);
            sdr_ln_p2_bf<<<NTOK, 256, 0, stream>>>(xbf, partials, gamma, beta, out);
        } else {
            sdr_gather_p1<false, false><<<NTOK, 256, 0, stream>>>(
                ids, nullptr, nullptr, Wt, out, partials);
            sdr_ln_p2_inplace<<<NTOK, 256, 0, stream>>>(out, partials, gamma, beta);
        }
    } else {
        sdr_gather_ln_notr<<<NTOK, 256, 0, stream>>>(ids, proj_w, gamma, beta, out);
    }
}